// Round 1
// baseline (868.678 us; speedup 1.0000x reference)
//
#include <hip/hip_runtime.h>
#include <math.h>

#define C 256
#define H 64
#define W 64
#define B 32
#define HW (H*W)
#define EPS 1e-5f
#define KSLAB 8
#define WPAD 260   // wslab row stride (floats): mult of 4 for float4, %32==4 for bank spread

__device__ __forceinline__ float gelu_exact(float z) {
    return 0.5f * z * (1.0f + erff(z * 0.70710678f));
}

__global__ __launch_bounds__(256) void pool_kernel(const float* __restrict__ x,
                                                   float* __restrict__ pooled) {
    int bc = blockIdx.x;                       // b*C + c
    const float4* p4 = (const float4*)(x + (size_t)bc * HW);
    int t = threadIdx.x;
    float s = 0.f;
    for (int i = t; i < HW/4; i += 256) {
        float4 v = p4[i];
        s += v.x + v.y + v.z + v.w;
    }
    for (int off = 32; off > 0; off >>= 1) s += __shfl_down(s, off, 64);
    __shared__ float wsum[4];
    if ((t & 63) == 0) wsum[t >> 6] = s;
    __syncthreads();
    if (t == 0) pooled[bc] = (wsum[0]+wsum[1]+wsum[2]+wsum[3]) * (1.f/HW);
}

__global__ void route_kernel(const float* __restrict__ pooled,
                             const float* __restrict__ rw,
                             const float* __restrict__ rb,
                             int* __restrict__ idx) {
    int b = threadIdx.x;
    if (b >= B) return;
    float l0 = rb[0], l1 = rb[1], l2 = rb[2];
    for (int c = 0; c < C; ++c) {
        float p = pooled[b*C + c];
        l0 += p * rw[c];
        l1 += p * rw[C + c];
        l2 += p * rw[2*C + c];
    }
    int best = 0; float bv = l0;
    if (l1 > bv) { bv = l1; best = 1; }
    if (l2 > bv) { bv = l2; best = 2; }
    idx[b] = best;   // softmax/temp monotone; w==1 always (tp/tp.sum == 1 for k=1)
}

// acc[i][j] = sum_k Wmat[(ty*8+i)*C + k] * featsrc[k*W + tx*8 + j]
__device__ __forceinline__ void gemm256(const float* __restrict__ Wmat,
                                        const float* __restrict__ featsrc,
                                        float* __restrict__ wslab,
                                        int tx, int ty, int t,
                                        float acc[8][8]) {
#pragma unroll
    for (int i = 0; i < 8; ++i)
#pragma unroll
        for (int j = 0; j < 8; ++j) acc[i][j] = 0.f;

    for (int k0 = 0; k0 < C; k0 += KSLAB) {
        __syncthreads();
        // stage W slab transposed: wslab[ciL][o] = Wmat[o][k0+ciL]
        // KSLAB*C/4 = 512 float4 loads, 2 per thread
#pragma unroll
        for (int it = 0; it < (KSLAB*C/4)/256; ++it) {
            int e4 = it*256 + t;
            int o  = e4 >> 1;          // KSLAB=8 -> 2 float4 per row
            int cq = e4 & 1;
            float4 v = *(const float4*)&Wmat[o*C + k0 + cq*4];
            wslab[(cq*4+0)*WPAD + o] = v.x;
            wslab[(cq*4+1)*WPAD + o] = v.y;
            wslab[(cq*4+2)*WPAD + o] = v.z;
            wslab[(cq*4+3)*WPAD + o] = v.w;
        }
        __syncthreads();
#pragma unroll
        for (int kk = 0; kk < KSLAB; ++kk) {
            int ci = k0 + kk;
            float f[8], p[8];
            *(float4*)&f[0] = *(const float4*)&featsrc[ci*W + tx*8];
            *(float4*)&f[4] = *(const float4*)&featsrc[ci*W + tx*8 + 4];
            *(float4*)&p[0] = *(const float4*)&wslab[kk*WPAD + ty*8];
            *(float4*)&p[4] = *(const float4*)&wslab[kk*WPAD + ty*8 + 4];
#pragma unroll
            for (int i = 0; i < 8; ++i)
#pragma unroll
                for (int j = 0; j < 8; ++j) acc[i][j] += p[i] * f[j];
        }
    }
}

__global__ __launch_bounds__(256, 2) void moe_kernel(
    const float* __restrict__ x, const int* __restrict__ idx,
    const float* __restrict__ e0k, const float* __restrict__ e0g, const float* __restrict__ e0b,
    const float* __restrict__ e0m, const float* __restrict__ e0v,
    const float* __restrict__ e0pw, const float* __restrict__ e0pb,
    const float* __restrict__ e1k, const float* __restrict__ e1g, const float* __restrict__ e1b,
    const float* __restrict__ e1m, const float* __restrict__ e1v,
    const float* __restrict__ e1pw, const float* __restrict__ e1pb,
    const float* __restrict__ e2k, const float* __restrict__ e2g, const float* __restrict__ e2b,
    const float* __restrict__ e2m, const float* __restrict__ e2v,
    const float* __restrict__ e2pw, const float* __restrict__ e2pb,
    float* __restrict__ out)
{
    __shared__ float featT[C*W];          // 64 KB: [ci][w]
    __shared__ float wslab[KSLAB*WPAD];   // 8.3 KB

    const int h = blockIdx.x, b = blockIdx.y;
    const int t = threadIdx.x;
    const int tx = t & 7;                 // w-group: w in [tx*8, tx*8+8)
    const int ty = t >> 3;                // o-group: o in [ty*8, ty*8+8)
    const int e = idx[b];

    if (e < 2) {
        const int dil = e + 1;
        const float* kk_ = (e == 0) ? e0k : e1k;
        const float* g   = (e == 0) ? e0g : e1g;
        const float* bb  = (e == 0) ? e0b : e1b;
        const float* mm  = (e == 0) ? e0m : e1m;
        const float* vv  = (e == 0) ? e0v : e1v;
        for (int it = 0; it < 64; ++it) {
            int li = it*256 + t;
            int ci = li >> 6, w = li & 63;        // ci wave-uniform
            const float* xp = x + (size_t)(b*C + ci) * HW;
            float a = 0.f;
#pragma unroll
            for (int ky = 0; ky < 3; ++ky) {
                int y = h + (ky - 1) * dil;
                if ((unsigned)y < H) {
#pragma unroll
                    for (int kx = 0; kx < 3; ++kx) {
                        int xw = w + (kx - 1) * dil;
                        if ((unsigned)xw < W)
                            a += kk_[ci*9 + ky*3 + kx] * xp[y*W + xw];
                    }
                }
            }
            float scale = g[ci] / sqrtf(vv[ci] + EPS);
            float z = (a - mm[ci]) * scale + bb[ci];
            featT[ci*W + w] = gelu_exact(z);
        }
        // gemm256's first __syncthreads covers the featT staging
    } else {
        // stage x row: featT[ci][w] = x[b][ci][h][w]
        for (int it = 0; it < 64; ++it) {
            int li = it*256 + t;
            int ci = li >> 6, w = li & 63;
            featT[ci*W + w] = x[((size_t)(b*C + ci) * H + h) * W + w];
        }
        float acc2[8][8];
        gemm256(e2k, featT, wslab, tx, ty, t, acc2);   // feat_pre = e2_k @ xrow
        __syncthreads();                                // all reads done before overwrite
#pragma unroll
        for (int i = 0; i < 8; ++i) {
            int ci = ty*8 + i;
            float scale = e2g[ci] / sqrtf(e2v[ci] + EPS);
#pragma unroll
            for (int j = 0; j < 8; ++j) {
                float z = (acc2[i][j] - e2m[ci]) * scale + e2b[ci];
                featT[ci*W + tx*8 + j] = gelu_exact(z);
            }
        }
    }

    const float* pw = (e == 0) ? e0pw : (e == 1 ? e1pw : e2pw);
    const float* pb = (e == 0) ? e0pb : (e == 1 ? e1pb : e2pb);

    float acc[8][8];
    gemm256(pw, featT, wslab, tx, ty, t, acc);

#pragma unroll
    for (int i = 0; i < 8; ++i) {
        int o = ty*8 + i;
        float bias = pb[o];
        float* op = out + ((size_t)(b*C + o) * H + h) * W + tx*8;
        float4 v0 = { acc[i][0]+bias, acc[i][1]+bias, acc[i][2]+bias, acc[i][3]+bias };
        float4 v1 = { acc[i][4]+bias, acc[i][5]+bias, acc[i][6]+bias, acc[i][7]+bias };
        *(float4*)op = v0;
        *(float4*)(op + 4) = v1;
    }
}

extern "C" void kernel_launch(void* const* d_in, const int* in_sizes, int n_in,
                              void* d_out, int out_size, void* d_ws, size_t ws_size,
                              hipStream_t stream) {
    const float* x    = (const float*)d_in[0];
    const float* rw   = (const float*)d_in[1];
    const float* rb   = (const float*)d_in[2];
    const float* e0k  = (const float*)d_in[3];
    const float* e0g  = (const float*)d_in[4];
    const float* e0b  = (const float*)d_in[5];
    const float* e0m  = (const float*)d_in[6];
    const float* e0v  = (const float*)d_in[7];
    const float* e0pw = (const float*)d_in[8];
    const float* e0pb = (const float*)d_in[9];
    const float* e1k  = (const float*)d_in[10];
    const float* e1g  = (const float*)d_in[11];
    const float* e1b  = (const float*)d_in[12];
    const float* e1m  = (const float*)d_in[13];
    const float* e1v  = (const float*)d_in[14];
    const float* e1pw = (const float*)d_in[15];
    const float* e1pb = (const float*)d_in[16];
    const float* e2k  = (const float*)d_in[17];
    const float* e2g  = (const float*)d_in[18];
    const float* e2b  = (const float*)d_in[19];
    const float* e2m  = (const float*)d_in[20];
    const float* e2v  = (const float*)d_in[21];
    const float* e2pw = (const float*)d_in[22];
    const float* e2pb = (const float*)d_in[23];
    float* out = (float*)d_out;

    float* pooled = (float*)d_ws;                          // B*C floats = 32 KB
    int*   idx    = (int*)((char*)d_ws + B*C*sizeof(float));

    pool_kernel<<<B*C, 256, 0, stream>>>(x, pooled);
    route_kernel<<<1, 64, 0, stream>>>(pooled, rw, rb, idx);
    moe_kernel<<<dim3(H, B), 256, 0, stream>>>(
        x, idx,
        e0k, e0g, e0b, e0m, e0v, e0pw, e0pb,
        e1k, e1g, e1b, e1m, e1v, e1pw, e1pb,
        e2k, e2g, e2b, e2m, e2v, e2pw, e2pb,
        out);
}

// Round 2
// 602.208 us; speedup vs baseline: 1.4425x; 1.4425x over previous
//
#include <hip/hip_runtime.h>
#include <math.h>

#define C 256
#define H 64
#define W 64
#define B 32
#define HW (H*W)
#define EPS 1e-5f

typedef __attribute__((ext_vector_type(8))) short short8;   // 8 bf16 = 4 VGPRs
typedef __attribute__((ext_vector_type(4))) short short4v;  // 4 bf16 = 2 VGPRs
typedef __attribute__((ext_vector_type(4))) float f32x4;

__device__ __forceinline__ float gelu_exact(float z) {
    return 0.5f * z * (1.0f + erff(z * 0.70710678f));
}

// fp32 -> bf16 round-to-nearest-even
__device__ __forceinline__ short f2bf(float f) {
    union { float f; unsigned u; } v; v.f = f;
    unsigned r = v.u + 0x7fffu + ((v.u >> 16) & 1u);
    return (short)(r >> 16);
}

__global__ __launch_bounds__(256) void pool_kernel(const float* __restrict__ x,
                                                   float* __restrict__ pooled) {
    int bc = blockIdx.x;
    const float4* p4 = (const float4*)(x + (size_t)bc * HW);
    int t = threadIdx.x;
    float s = 0.f;
    for (int i = t; i < HW/4; i += 256) {
        float4 v = p4[i];
        s += v.x + v.y + v.z + v.w;
    }
    for (int off = 32; off > 0; off >>= 1) s += __shfl_down(s, off, 64);
    __shared__ float wsum[4];
    if ((t & 63) == 0) wsum[t >> 6] = s;
    __syncthreads();
    if (t == 0) pooled[bc] = (wsum[0]+wsum[1]+wsum[2]+wsum[3]) * (1.f/HW);
}

__global__ void route_kernel(const float* __restrict__ pooled,
                             const float* __restrict__ rw,
                             const float* __restrict__ rb,
                             int* __restrict__ idx) {
    int b = threadIdx.x;
    if (b >= B) return;
    float l0 = rb[0], l1 = rb[1], l2 = rb[2];
    for (int c = 0; c < C; ++c) {
        float p = pooled[b*C + c];
        l0 += p * rw[c];
        l1 += p * rw[C + c];
        l2 += p * rw[2*C + c];
    }
    int best = 0; float bv = l0;
    if (l1 > bv) { bv = l1; best = 1; }
    if (l2 > bv) { bv = l2; best = 2; }
    idx[b] = best;   // softmax/temp monotone; w==1 always for top-1
}

// Pack 4 matrices (pw0, pw1, pw2, e2_k), each C*C fp32 row-major [o][ci],
// into MFMA fragment order: chunk (kt, mt): lane holds M[o = mt*16 + (lane&15)]
// [ci = kt*32 + (lane>>4)*8 + j], j=0..7 -> one 16B chunk per lane.
__global__ __launch_bounds__(256) void prep_pack(
    const float* __restrict__ s0, const float* __restrict__ s1,
    const float* __restrict__ s2, const float* __restrict__ s3,
    short* __restrict__ apackAll) {
    int gid = blockIdx.x * 256 + threadIdx.x;       // 0..32767
    int mat = gid >> 13;                            // 8192 chunks per matrix
    int c   = gid & 8191;
    int lane = c & 63;
    int ktmt = c >> 6;
    int mt = ktmt & 15, kt = ktmt >> 4;
    int o  = mt*16 + (lane & 15);
    int ci = kt*32 + (lane >> 4)*8;
    const float* src = (mat == 0) ? s0 : (mat == 1) ? s1 : (mat == 2) ? s2 : s3;
    const float* p = src + o*C + ci;
    short8 v;
#pragma unroll
    for (int j = 0; j < 8; ++j) v[j] = f2bf(p[j]);
    *(short8*)&apackAll[(size_t)gid * 8] = v;
}

// folded BN: z = a*sc + sh
__global__ void prep_scale(
    const float* __restrict__ g0, const float* __restrict__ b0,
    const float* __restrict__ m0, const float* __restrict__ v0,
    const float* __restrict__ g1, const float* __restrict__ b1,
    const float* __restrict__ m1, const float* __restrict__ v1,
    const float* __restrict__ g2, const float* __restrict__ b2,
    const float* __restrict__ m2, const float* __restrict__ v2,
    float* __restrict__ scAll, float* __restrict__ shAll) {
    int i = blockIdx.x * 256 + threadIdx.x;         // 0..767
    if (i >= 3*C) return;
    int e = i >> 8, c = i & 255;
    const float *g = (e==0)?g0:(e==1)?g1:g2;
    const float *bb= (e==0)?b0:(e==1)?b1:b2;
    const float *mm= (e==0)?m0:(e==1)?m1:m2;
    const float *vv= (e==0)?v0:(e==1)?v1:v2;
    float s = g[c] / sqrtf(vv[c] + EPS);
    scAll[i] = s;
    shAll[i] = bb[c] - mm[c]*s;
}

// Block = (h, b). 256 threads = 4 waves. Wave `wid` stages feat fragments for
// w-tile wid; GEMM2 computes D[w][o] = sum_ci feat[ci][w] * pw[o][ci] via
// mfma(A=feat_frag, B=pw_frag) so rows = w -> coalesced float4 stores.
__global__ __launch_bounds__(256, 2) void moe_mfma(
    const float* __restrict__ x, const int* __restrict__ idx,
    const float* __restrict__ e0k, const float* __restrict__ e1k,
    const short* __restrict__ apackAll,   // [4][8kt][16mt][64lane][8] bf16
    const float* __restrict__ scAll, const float* __restrict__ shAll,
    const float* __restrict__ e0pb, const float* __restrict__ e1pb,
    const float* __restrict__ e2pb,
    float* __restrict__ out)
{
    __shared__ short featB[8*4*64*8];   // 32 KB: chunk(kt,wt) -> 64 lanes x 16B

    const int h = blockIdx.x, b = blockIdx.y;
    const int t = threadIdx.x;
    const int lane = t & 63, wid = t >> 6;
    const int l15 = lane & 15, quad = lane >> 4;
    const int e = idx[b];

    const short* apackE = apackAll + (size_t)e * 65536;     // pw fragments
    const float* sc = scAll + e*C;
    const float* sh = shAll + e*C;
    const int w = wid*16 + l15;    // this thread's w column for staging

    if (e < 2) {
        const int dil = e + 1;
        const float* kker = (e == 0) ? e0k : e1k;
#pragma unroll 2
        for (int kt = 0; kt < 8; ++kt) {
            int ci0 = kt*32 + quad*8;
            short8 res;
#pragma unroll
            for (int j = 0; j < 8; ++j) {
                int ci = ci0 + j;
                const float* xp = x + (size_t)(b*C + ci) * HW;
                const float* kp = kker + ci*9;
                float a = 0.f;
#pragma unroll
                for (int ky = 0; ky < 3; ++ky) {
                    int y = h + (ky - 1)*dil;
                    if ((unsigned)y < H) {
                        const float* row = xp + y*W;
#pragma unroll
                        for (int kx = 0; kx < 3; ++kx) {
                            int xw = w + (kx - 1)*dil;
                            if ((unsigned)xw < W) a += kp[ky*3+kx] * row[xw];
                        }
                    }
                }
                res[j] = f2bf(gelu_exact(a*sc[ci] + sh[ci]));
            }
            *(short8*)&featB[((kt*4 + wid)*64 + lane)*8] = res;
        }
        __syncthreads();
    } else {
        // stage x as fragments (bf16)
#pragma unroll 2
        for (int kt = 0; kt < 8; ++kt) {
            int ci0 = kt*32 + quad*8;
            short8 res;
#pragma unroll
            for (int j = 0; j < 8; ++j)
                res[j] = f2bf(x[((size_t)(b*C + ci0 + j)*H + h)*W + w]);
            *(short8*)&featB[((kt*4 + wid)*64 + lane)*8] = res;
        }
        __syncthreads();

        // GEMM1: D[ci_out][w] = e2_k @ x_row; A = e2k frags, B = x frags
        const short* a2 = apackAll + (size_t)3 * 65536;
        f32x4 acc1[16];
#pragma unroll
        for (int i = 0; i < 16; ++i) acc1[i] = (f32x4){0.f,0.f,0.f,0.f};
        for (int kt = 0; kt < 8; ++kt) {
            short8 af[4], bf[4];
#pragma unroll
            for (int i = 0; i < 4; ++i)
                af[i] = *(const short8*)&a2[((size_t)(kt*16 + wid*4 + i)*64 + lane)*8];
#pragma unroll
            for (int wt = 0; wt < 4; ++wt)
                bf[wt] = *(const short8*)&featB[((kt*4 + wt)*64 + lane)*8];
#pragma unroll
            for (int i = 0; i < 4; ++i)
#pragma unroll
                for (int wt = 0; wt < 4; ++wt)
                    acc1[i*4+wt] = __builtin_amdgcn_mfma_f32_16x16x32_bf16(
                        af[i], bf[wt], acc1[i*4+wt], 0, 0, 0);
        }
        __syncthreads();   // all reads of featB done before overwrite

        // BN + gelu + repack D (C-layout) into fragment layout
        const float* sc2 = scAll + 2*C;
        const float* sh2 = shAll + 2*C;
#pragma unroll
        for (int i = 0; i < 4; ++i) {
            int cibase = (wid*4 + i)*16 + quad*4;    // 4 consecutive ci_out
            float4 s4 = *(const float4*)&sc2[cibase];
            float4 h4 = *(const float4*)&sh2[cibase];
            float sv[4] = {s4.x, s4.y, s4.z, s4.w};
            float hv[4] = {h4.x, h4.y, h4.z, h4.w};
            int ktp = cibase >> 5;
            int qp  = (cibase >> 3) & 3;
            int j0  = cibase & 7;                    // 0 or 4
#pragma unroll
            for (int wt = 0; wt < 4; ++wt) {
                short4v pk;
#pragma unroll
                for (int r = 0; r < 4; ++r) {
                    float z = acc1[i*4+wt][r]*sv[r] + hv[r];
                    pk[r] = f2bf(gelu_exact(z));
                }
                *(short4v*)&featB[((ktp*4 + wt)*64 + qp*16 + l15)*8 + j0] = pk;
            }
        }
        __syncthreads();
    }

    // GEMM2: D[w][o]; A = feat frags (LDS), B = pw frags (global, L2-hot)
    f32x4 acc[16];
#pragma unroll
    for (int i = 0; i < 16; ++i) acc[i] = (f32x4){0.f,0.f,0.f,0.f};
    for (int kt = 0; kt < 8; ++kt) {
        short8 af[4], bf[4];
#pragma unroll
        for (int wt = 0; wt < 4; ++wt)
            af[wt] = *(const short8*)&featB[((kt*4 + wt)*64 + lane)*8];
#pragma unroll
        for (int i = 0; i < 4; ++i)
            bf[i] = *(const short8*)&apackE[((size_t)(kt*16 + wid*4 + i)*64 + lane)*8];
#pragma unroll
        for (int i = 0; i < 4; ++i)
#pragma unroll
            for (int wt = 0; wt < 4; ++wt)
                acc[i*4+wt] = __builtin_amdgcn_mfma_f32_16x16x32_bf16(
                    af[wt], bf[i], acc[i*4+wt], 0, 0, 0);
    }

    const float* pb = (e == 0) ? e0pb : (e == 1) ? e1pb : e2pb;
#pragma unroll
    for (int i = 0; i < 4; ++i) {
        int o = (wid*4 + i)*16 + l15;
        float pbv = pb[o];
        float* obase = out + ((size_t)(b*C + o)*H + h)*W;
#pragma unroll
        for (int wt = 0; wt < 4; ++wt) {
            int w0 = wt*16 + quad*4;
            f32x4 a = acc[i*4+wt];
            float4 v = {a[0]+pbv, a[1]+pbv, a[2]+pbv, a[3]+pbv};
            *(float4*)(obase + w0) = v;
        }
    }
}

extern "C" void kernel_launch(void* const* d_in, const int* in_sizes, int n_in,
                              void* d_out, int out_size, void* d_ws, size_t ws_size,
                              hipStream_t stream) {
    const float* x    = (const float*)d_in[0];
    const float* rw   = (const float*)d_in[1];
    const float* rb   = (const float*)d_in[2];
    const float* e0k  = (const float*)d_in[3];
    const float* e0g  = (const float*)d_in[4];
    const float* e0b  = (const float*)d_in[5];
    const float* e0m  = (const float*)d_in[6];
    const float* e0v  = (const float*)d_in[7];
    const float* e0pw = (const float*)d_in[8];
    const float* e0pb = (const float*)d_in[9];
    const float* e1k  = (const float*)d_in[10];
    const float* e1g  = (const float*)d_in[11];
    const float* e1b  = (const float*)d_in[12];
    const float* e1m  = (const float*)d_in[13];
    const float* e1v  = (const float*)d_in[14];
    const float* e1pw = (const float*)d_in[15];
    const float* e1pb = (const float*)d_in[16];
    const float* e2k  = (const float*)d_in[17];
    const float* e2g  = (const float*)d_in[18];
    const float* e2b  = (const float*)d_in[19];
    const float* e2m  = (const float*)d_in[20];
    const float* e2v  = (const float*)d_in[21];
    const float* e2pw = (const float*)d_in[22];
    const float* e2pb = (const float*)d_in[23];
    float* out = (float*)d_out;

    // ws layout
    char* wsb = (char*)d_ws;
    float* pooled   = (float*)wsb;                         // 32768 B
    int*   idx      = (int*)(wsb + 32768);                 // 128 B
    float* scAll    = (float*)(wsb + 32896);               // 3072 B
    float* shAll    = (float*)(wsb + 35968);               // 3072 B
    short* apackAll = (short*)(wsb + 39040);               // 4*128KB = 524288 B

    pool_kernel<<<B*C, 256, 0, stream>>>(x, pooled);
    route_kernel<<<1, 64, 0, stream>>>(pooled, rw, rb, idx);
    prep_pack<<<128, 256, 0, stream>>>(e0pw, e1pw, e2pw, e2k, apackAll);
    prep_scale<<<3, 256, 0, stream>>>(e0g, e0b, e0m, e0v,
                                      e1g, e1b, e1m, e1v,
                                      e2g, e2b, e2m, e2v, scAll, shAll);
    moe_mfma<<<dim3(H, B), 256, 0, stream>>>(
        x, idx, e0k, e1k, apackAll, scAll, shAll, e0pb, e1pb, e2pb, out);
}

// Round 3
// 381.780 us; speedup vs baseline: 2.2753x; 1.5774x over previous
//
#include <hip/hip_runtime.h>
#include <math.h>

#define C 256
#define H 64
#define W 64
#define B 32
#define HW (H*W)
#define EPS 1e-5f
#define LSTR 72   // LDS feat row stride in shorts (144 B: 16B-aligned, swizzle-friendly)

typedef __attribute__((ext_vector_type(8))) short short8;   // 8 bf16
typedef __attribute__((ext_vector_type(4))) short short4v;  // 4 bf16
typedef __attribute__((ext_vector_type(4))) float f32x4;

__device__ __forceinline__ float gelu_exact(float z) {
    return 0.5f * z * (1.0f + erff(z * 0.70710678f));
}
__device__ __forceinline__ short f2bf(float f) {
    union { float f; unsigned u; } v; v.f = f;
    unsigned r = v.u + 0x7fffu + ((v.u >> 16) & 1u);
    return (short)(r >> 16);
}

__global__ __launch_bounds__(256) void pool_kernel(const float* __restrict__ x,
                                                   float* __restrict__ pooled) {
    int bc = blockIdx.x;
    const float4* p4 = (const float4*)(x + (size_t)bc * HW);
    int t = threadIdx.x;
    float s = 0.f;
    for (int i = t; i < HW/4; i += 256) {
        float4 v = p4[i];
        s += v.x + v.y + v.z + v.w;
    }
    for (int off = 32; off > 0; off >>= 1) s += __shfl_down(s, off, 64);
    __shared__ float wsum[4];
    if ((t & 63) == 0) wsum[t >> 6] = s;
    __syncthreads();
    if (t == 0) pooled[bc] = (wsum[0]+wsum[1]+wsum[2]+wsum[3]) * (1.f/HW);
}

// one block per b; 3 waves, one per expert logit; shuffle-reduce dot product
__global__ void route_kernel(const float* __restrict__ pooled,
                             const float* __restrict__ rw,
                             const float* __restrict__ rb,
                             int* __restrict__ idx) {
    int b = blockIdx.x;
    int t = threadIdx.x;           // 0..191
    int e = t >> 6, lane = t & 63;
    const float* p = pooled + b*C;
    const float* w = rw + e*C;
    float s = 0.f;
#pragma unroll
    for (int i = 0; i < 4; ++i) s += p[lane + i*64] * w[lane + i*64];
    for (int off = 32; off > 0; off >>= 1) s += __shfl_down(s, off, 64);
    __shared__ float lg[3];
    if (lane == 0) lg[e] = s + rb[e];
    __syncthreads();
    if (t == 0) {
        int best = 0; float bv = lg[0];
        if (lg[1] > bv) { bv = lg[1]; best = 1; }
        if (lg[2] > bv) { bv = lg[2]; best = 2; }
        idx[b] = best;   // softmax/temp monotone; w==1 always for top-1
    }
}

// blocks 0..127: pack pw0,pw1,pw2,e2k (C*C fp32 row-major [o][ci]) into bf16
// fragment order: chunk (kt,mt): lane holds M[o=mt*16+(lane&15)][ci=kt*32+(lane>>4)*8+j].
// block 128: fold BN into conv weights (kf = k*scale, pad stride 12) + sc/sh tables.
__global__ __launch_bounds__(256) void prep_kernel(
    const float* __restrict__ s0, const float* __restrict__ s1,
    const float* __restrict__ s2, const float* __restrict__ s3,
    const float* __restrict__ e0k, const float* __restrict__ e1k,
    const float* __restrict__ g0, const float* __restrict__ b0,
    const float* __restrict__ m0, const float* __restrict__ v0,
    const float* __restrict__ g1, const float* __restrict__ b1,
    const float* __restrict__ m1, const float* __restrict__ v1,
    const float* __restrict__ g2, const float* __restrict__ b2,
    const float* __restrict__ m2, const float* __restrict__ v2,
    short* __restrict__ apackAll, float* __restrict__ kf0, float* __restrict__ kf1,
    float* __restrict__ scAll, float* __restrict__ shAll)
{
    if (blockIdx.x < 128) {
        int gid = blockIdx.x * 256 + threadIdx.x;       // 0..32767
        int mat = gid >> 13;
        int c   = gid & 8191;
        int lane = c & 63;
        int ktmt = c >> 6;
        int mt = ktmt & 15, kt = ktmt >> 4;
        int o  = mt*16 + (lane & 15);
        int ci = kt*32 + (lane >> 4)*8;
        const float* src = (mat == 0) ? s0 : (mat == 1) ? s1 : (mat == 2) ? s2 : s3;
        const float* p = src + o*C + ci;
        short8 v;
#pragma unroll
        for (int j = 0; j < 8; ++j) v[j] = f2bf(p[j]);
        *(short8*)&apackAll[(size_t)gid * 8] = v;
    } else {
        int t = threadIdx.x;   // = ci
        {
            float s = g0[t] / sqrtf(v0[t] + EPS);
            scAll[t] = s; shAll[t] = b0[t] - m0[t]*s;
#pragma unroll
            for (int j = 0; j < 9; ++j) kf0[t*12+j] = e0k[t*9+j]*s;
            kf0[t*12+9] = 0.f; kf0[t*12+10] = 0.f; kf0[t*12+11] = 0.f;
        }
        {
            float s = g1[t] / sqrtf(v1[t] + EPS);
            scAll[C+t] = s; shAll[C+t] = b1[t] - m1[t]*s;
#pragma unroll
            for (int j = 0; j < 9; ++j) kf1[t*12+j] = e1k[t*9+j]*s;
            kf1[t*12+9] = 0.f; kf1[t*12+10] = 0.f; kf1[t*12+11] = 0.f;
        }
        {
            float s = g2[t] / sqrtf(v2[t] + EPS);
            scAll[2*C+t] = s; shAll[2*C+t] = b2[t] - m2[t]*s;
        }
    }
}

// conv for dilation DIL (compile-time so fr[] indexing stays in registers)
template<int DIL>
__device__ __forceinline__ void conv_rows(const float* __restrict__ x,
                                          const float* __restrict__ kf,
                                          const float* __restrict__ sh,
                                          short* __restrict__ lds,
                                          int b, int h, int t) {
    const int strip = t & 7;
    const int w0 = strip * 8;
    const int cib = t >> 3;
#pragma unroll 1
    for (int iter = 0; iter < 8; ++iter) {
        int ci = iter*32 + cib;
        const float* xpl = x + (size_t)(b*C + ci) * HW;
        float fr[3][16];
        bool rv[3];
#pragma unroll
        for (int ky = 0; ky < 3; ++ky) {
            int y = h + (ky - 1)*DIL;
            rv[ky] = ((unsigned)y < H);      // wave-uniform
            if (rv[ky]) {
                const float* row = xpl + y*W;
                float4 fa = (strip > 0) ? *(const float4*)(row + w0 - 4) : float4{0,0,0,0};
                float4 fb = *(const float4*)(row + w0);
                float4 fc = *(const float4*)(row + w0 + 4);
                float4 fd = (strip < 7) ? *(const float4*)(row + w0 + 8) : float4{0,0,0,0};
                fr[ky][0]=fa.x; fr[ky][1]=fa.y; fr[ky][2]=fa.z; fr[ky][3]=fa.w;
                fr[ky][4]=fb.x; fr[ky][5]=fb.y; fr[ky][6]=fb.z; fr[ky][7]=fb.w;
                fr[ky][8]=fc.x; fr[ky][9]=fc.y; fr[ky][10]=fc.z; fr[ky][11]=fc.w;
                fr[ky][12]=fd.x; fr[ky][13]=fd.y; fr[ky][14]=fd.z; fr[ky][15]=fd.w;
            }
        }
        float4 k0 = *(const float4*)(kf + ci*12);
        float4 k1v = *(const float4*)(kf + ci*12 + 4);
        float wk[9] = {k0.x,k0.y,k0.z,k0.w,k1v.x,k1v.y,k1v.z,k1v.w, kf[ci*12+8]};
        float acc8[8] = {0,0,0,0,0,0,0,0};
#pragma unroll
        for (int ky = 0; ky < 3; ++ky) {
            if (rv[ky]) {
#pragma unroll
                for (int kx = 0; kx < 3; ++kx) {
                    float wv = wk[ky*3+kx];
                    const int base = 4 + (kx - 1)*DIL;   // compile-time
#pragma unroll
                    for (int j = 0; j < 8; ++j) acc8[j] += wv * fr[ky][base + j];
                }
            }
        }
        float shv = sh[ci];
        int w0s = w0 ^ ((((unsigned)ci >> 3) & 3) << 4);
        short8 res;
#pragma unroll
        for (int j = 0; j < 8; ++j) res[j] = f2bf(gelu_exact(acc8[j] + shv));
        *(short8*)&lds[ci*LSTR + w0s] = res;
    }
}

// Block = (h, b). Produces feat (bf16, MFMA A/B-fragment layout) for the selected
// expert: e<2 -> dwconv+BN+gelu; e==2 -> in-block e2k GEMM (bf16 x) + BN + gelu.
// featfrag chunk (b, pt, kt): lane holds feat[p=pt*16+(lane&15)][ci=kt*32+(lane>>4)*8+j].
__global__ __launch_bounds__(256) void k1_feat(
    const float* __restrict__ x, const int* __restrict__ idx,
    const float* __restrict__ kf0, const float* __restrict__ kf1,
    const float* __restrict__ scAll, const float* __restrict__ shAll,
    const short* __restrict__ apackAll,
    short* __restrict__ featfrag)
{
    __shared__ short lds[C*LSTR];   // 36 KB, [ci][w^swizzle]
    const int h = blockIdx.x, b = blockIdx.y;
    const int t = threadIdx.x;
    const int lane = t & 63, wid = t >> 6;
    const int l15 = lane & 15, quad = lane >> 4;
    const int e = idx[b];

    if (e < 2) {
        if (e == 0) conv_rows<1>(x, kf0, shAll,     lds, b, h, t);
        else        conv_rows<2>(x, kf1, shAll + C, lds, b, h, t);
        __syncthreads();
        // transpose LDS [ci][w] -> fragment chunks (coalesced 16B/lane stores)
#pragma unroll
        for (int itr = 0; itr < 8; ++itr) {
            int chunk = itr*4 + wid;          // 0..31
            int kt = chunk & 7, pt = chunk >> 3;
            int wv = pt*16 + l15;
            int cb = kt*32 + quad*8;
            short8 v;
#pragma unroll
            for (int r = 0; r < 8; ++r) {
                int ci = cb + r;
                v[r] = lds[ci*LSTR + (wv ^ ((((unsigned)ci >> 3) & 3) << 4))];
            }
            *(short8*)&featfrag[(((size_t)(b*C + h*4 + pt)*8 + kt)*64 + lane)*8] = v;
        }
    } else {
        // stage x (bf16) into LDS
        const int strip = t & 7, w0 = strip*8, cib = t >> 3;
#pragma unroll 1
        for (int iter = 0; iter < 8; ++iter) {
            int ci = iter*32 + cib;
            const float* row = x + ((size_t)(b*C + ci)*H + h)*W;
            float4 fa = *(const float4*)(row + w0);
            float4 fb = *(const float4*)(row + w0 + 4);
            short8 res = { f2bf(fa.x), f2bf(fa.y), f2bf(fa.z), f2bf(fa.w),
                           f2bf(fb.x), f2bf(fb.y), f2bf(fb.z), f2bf(fb.w) };
            int w0s = w0 ^ ((((unsigned)ci >> 3) & 3) << 4);
            *(short8*)&lds[ci*LSTR + w0s] = res;
        }
        __syncthreads();
        // GEMM1: D[co][p] = e2k @ x_row.  A = e2k frags (global, L2-hot), B = x frags (LDS)
        const short* a2 = apackAll + (size_t)3 * 65536;
        f32x4 acc[4][4];
#pragma unroll
        for (int i = 0; i < 4; ++i)
#pragma unroll
            for (int wt = 0; wt < 4; ++wt) acc[i][wt] = (f32x4){0.f,0.f,0.f,0.f};
        for (int kt = 0; kt < 8; ++kt) {
            short8 bf[4];
#pragma unroll
            for (int wt = 0; wt < 4; ++wt) {
                int wv = (wt*16 + l15) ^ (quad << 4);   // (ci>>3)&3 == quad here
                int cb = kt*32 + quad*8;
                short8 v;
#pragma unroll
                for (int r = 0; r < 8; ++r) v[r] = lds[(cb + r)*LSTR + wv];
                bf[wt] = v;
            }
            short8 af[4];
#pragma unroll
            for (int i = 0; i < 4; ++i)
                af[i] = *(const short8*)&a2[((size_t)(kt*16 + wid*4 + i)*64 + lane)*8];
#pragma unroll
            for (int i = 0; i < 4; ++i)
#pragma unroll
                for (int wt = 0; wt < 4; ++wt)
                    acc[i][wt] = __builtin_amdgcn_mfma_f32_16x16x32_bf16(
                        af[i], bf[wt], acc[i][wt], 0, 0, 0);
        }
        // BN + gelu + repack D (rows=co, cols=p) into fragment layout, direct to global
        const float* sc2 = scAll + 2*C;
        const float* sh2 = shAll + 2*C;
#pragma unroll
        for (int i = 0; i < 4; ++i) {
            int cob = wid*64 + i*16 + quad*4;     // +r = co
            float4 s4 = *(const float4*)&sc2[cob];
            float4 h4 = *(const float4*)&sh2[cob];
            int kt2 = cob >> 5;
            int lq  = (((cob >> 3) & 3) << 4) + l15;
            int j0  = cob & 7;                    // 0 or 4
#pragma unroll
            for (int wt = 0; wt < 4; ++wt) {
                short4v pk;
                pk[0] = f2bf(gelu_exact(acc[i][wt][0]*s4.x + h4.x));
                pk[1] = f2bf(gelu_exact(acc[i][wt][1]*s4.y + h4.y));
                pk[2] = f2bf(gelu_exact(acc[i][wt][2]*s4.z + h4.z));
                pk[3] = f2bf(gelu_exact(acc[i][wt][3]*s4.w + h4.w));
                *(short4v*)&featfrag[(((size_t)(b*C + h*4 + wt)*8 + kt2)*64 + lq)*8 + j0] = pk;
            }
        }
    }
}

// Fragment-direct GEMM, no LDS, no syncthreads. Block tile 128p x 128o.
// D[p][o] = sum_ci feat[p][ci] * pw[o][ci]; A = feat frags, B = pw frags.
__global__ __launch_bounds__(256) void k2b_out(
    const int* __restrict__ idx, const short* __restrict__ featfrag,
    const short* __restrict__ apackAll,
    const float* __restrict__ e0pb, const float* __restrict__ e1pb,
    const float* __restrict__ e2pb,
    float* __restrict__ out)
{
    const int pblk = blockIdx.x;      // 0..31
    const int oblk = blockIdx.y;      // 0..1
    const int b = blockIdx.z;
    const int t = threadIdx.x, lane = t & 63, wid = t >> 6;
    const int l15 = lane & 15, quad = lane >> 4;
    const int e = idx[b];
    const short* pwf = apackAll + (size_t)e * 65536;
    const float* pb = (e == 0) ? e0pb : (e == 1) ? e1pb : e2pb;

    f32x4 acc[2][8];
#pragma unroll
    for (int a = 0; a < 2; ++a)
#pragma unroll
        for (int i = 0; i < 8; ++i) acc[a][i] = (f32x4){0.f,0.f,0.f,0.f};

    const short* fbase = featfrag + ((size_t)(b*C + pblk*8 + wid*2)*8)*512;
    for (int kt = 0; kt < 8; ++kt) {
        short8 af[2];
#pragma unroll
        for (int a = 0; a < 2; ++a)
            af[a] = *(const short8*)&fbase[((size_t)(a*8 + kt)*64 + lane)*8];
        short8 bf[8];
#pragma unroll
        for (int i = 0; i < 8; ++i)
            bf[i] = *(const short8*)&pwf[((size_t)(kt*16 + oblk*8 + i)*64 + lane)*8];
#pragma unroll
        for (int a = 0; a < 2; ++a)
#pragma unroll
            for (int i = 0; i < 8; ++i)
                acc[a][i] = __builtin_amdgcn_mfma_f32_16x16x32_bf16(
                    af[a], bf[i], acc[a][i], 0, 0, 0);
    }

#pragma unroll
    for (int i = 0; i < 8; ++i) {
        int o = oblk*128 + i*16 + l15;
        float pbv = pb[o];
#pragma unroll
        for (int a = 0; a < 2; ++a) {
            int p = pblk*128 + wid*32 + a*16 + quad*4;
            f32x4 v = acc[a][i];
            float4 sv = {v[0]+pbv, v[1]+pbv, v[2]+pbv, v[3]+pbv};
            *(float4*)(out + (size_t)(b*C + o)*HW + p) = sv;
        }
    }
}

extern "C" void kernel_launch(void* const* d_in, const int* in_sizes, int n_in,
                              void* d_out, int out_size, void* d_ws, size_t ws_size,
                              hipStream_t stream) {
    const float* x    = (const float*)d_in[0];
    const float* rw   = (const float*)d_in[1];
    const float* rb   = (const float*)d_in[2];
    const float* e0k  = (const float*)d_in[3];
    const float* e0g  = (const float*)d_in[4];
    const float* e0b  = (const float*)d_in[5];
    const float* e0m  = (const float*)d_in[6];
    const float* e0v  = (const float*)d_in[7];
    const float* e0pw = (const float*)d_in[8];
    const float* e0pb = (const float*)d_in[9];
    const float* e1k  = (const float*)d_in[10];
    const float* e1g  = (const float*)d_in[11];
    const float* e1b  = (const float*)d_in[12];
    const float* e1m  = (const float*)d_in[13];
    const float* e1v  = (const float*)d_in[14];
    const float* e1pw = (const float*)d_in[15];
    const float* e1pb = (const float*)d_in[16];
    const float* e2k  = (const float*)d_in[17];
    const float* e2g  = (const float*)d_in[18];
    const float* e2b  = (const float*)d_in[19];
    const float* e2m  = (const float*)d_in[20];
    const float* e2v  = (const float*)d_in[21];
    const float* e2pw = (const float*)d_in[22];
    const float* e2pb = (const float*)d_in[23];
    float* out = (float*)d_out;

    char* wsb = (char*)d_ws;
    float* pooled   = (float*)wsb;                       // 32768 B
    int*   idx      = (int*)(wsb + 32768);               // 128 B
    float* scAll    = (float*)(wsb + 32896);             // 3072 B
    float* shAll    = (float*)(wsb + 35968);             // 3072 B
    float* kf0      = (float*)(wsb + 39040);             // 12288 B
    float* kf1      = (float*)(wsb + 51328);             // 12288 B
    short* apackAll = (short*)(wsb + 63616);             // 524288 B
    short* featfrag = (short*)(wsb + (1u << 20));        // 64 MB

    pool_kernel<<<B*C, 256, 0, stream>>>(x, pooled);
    route_kernel<<<B, 192, 0, stream>>>(pooled, rw, rb, idx);
    prep_kernel<<<129, 256, 0, stream>>>(e0pw, e1pw, e2pw, e2k, e0k, e1k,
                                         e0g, e0b, e0m, e0v,
                                         e1g, e1b, e1m, e1v,
                                         e2g, e2b, e2m, e2v,
                                         apackAll, kf0, kf1, scAll, shAll);
    k1_feat<<<dim3(H, B), 256, 0, stream>>>(x, idx, kf0, kf1, scAll, shAll,
                                            apackAll, featfrag);
    k2b_out<<<dim3(32, 2, B), 256, 0, stream>>>(idx, featfrag, apackAll,
                                                e0pb, e1pb, e2pb, out);
}